// Round 2
// baseline (158.326 us; speedup 1.0000x reference)
//
#include <hip/hip_runtime.h>

#define H2    1024
#define LSRC  1024
#define BATCH 64

__device__ __forceinline__ float fast_tanh(float x) {
  // tanh(x) = 1 - 2/(exp(2x)+1); saturates correctly (exp->inf => 1, exp->0 => -1)
  float e2 = __expf(2.0f * x);
  return 1.0f - 2.0f * __builtin_amdgcn_rcpf(e2 + 1.0f);
}

// dec[b][h] = sum_k s[b][k] * W[h][k] + bias[h]   (s: [64,1024], W: [1024,1024])
// grid = 64 blocks (16 h each), block = 256. LDS-tiled over k, float4 LDS reads.
__global__ __launch_bounds__(256) void dec_kernel(
    const float* __restrict__ s, const float* __restrict__ W,
    const float* __restrict__ bias, float* __restrict__ dec) {
  __shared__ float s_lds[BATCH][132];  // 128 k + 4 pad (keeps 16B align, breaks pow2 stride)
  __shared__ float w_lds[16][128];     // broadcast reads
  const int t  = threadIdx.x;
  const int h0 = blockIdx.x * 16;
  const int bi = t & 63;
  const int hg = t >> 6;  // 0..3
  float4 acc = {0.f, 0.f, 0.f, 0.f};   // h = h0 + hg + {0,4,8,12}... components map below
  for (int k0 = 0; k0 < H2; k0 += 128) {
    __syncthreads();
    for (int idx = t; idx < BATCH * 32; idx += 256) {      // 2048 float4, 8/thread
      int r = idx >> 5, c = idx & 31;
      float4 x = ((const float4*)(s + (size_t)r * H2 + k0))[c];
      *(float4*)&s_lds[r][c * 4] = x;
    }
    for (int idx = t; idx < 16 * 32; idx += 256) {         // 512 float4, 2/thread
      int r = idx >> 5, c = idx & 31;
      float4 x = ((const float4*)(W + (size_t)(h0 + r) * H2 + k0))[c];
      *(float4*)&w_lds[r][c * 4] = x;
    }
    __syncthreads();
    for (int kq = 0; kq < 32; ++kq) {
      float4 sv = *(const float4*)&s_lds[bi][kq * 4];
      float4 w0 = *(const float4*)&w_lds[hg][kq * 4];
      float4 w1 = *(const float4*)&w_lds[hg + 4][kq * 4];
      float4 w2 = *(const float4*)&w_lds[hg + 8][kq * 4];
      float4 w3 = *(const float4*)&w_lds[hg + 12][kq * 4];
      acc.x += sv.x * w0.x + sv.y * w0.y + sv.z * w0.z + sv.w * w0.w;
      acc.y += sv.x * w1.x + sv.y * w1.y + sv.z * w1.z + sv.w * w1.w;
      acc.z += sv.x * w2.x + sv.y * w2.y + sv.z * w2.z + sv.w * w2.w;
      acc.w += sv.x * w3.x + sv.y * w3.y + sv.z * w3.z + sv.w * w3.w;
    }
  }
  dec[bi * H2 + h0 + hg]      = acc.x + bias[h0 + hg];
  dec[bi * H2 + h0 + hg + 4]  = acc.y + bias[h0 + hg + 4];
  dec[bi * H2 + h0 + hg + 8]  = acc.z + bias[h0 + hg + 8];
  dec[bi * H2 + h0 + hg + 12] = acc.w + bias[h0 + hg + 12];
}

// e[row] = sum_h tanh(ef[row][h] + dec[b][h]) * v[h]
// One wave per 8 rows of the same b; dec/v fragments register-cached once.
// grid = 2048 blocks (64 b x 32 blocks), block = 256 (4 waves x 8 rows = 32 rows).
__global__ __launch_bounds__(256) void e_kernel(
    const float* __restrict__ ef, const float* __restrict__ dec,
    const float* __restrict__ v, float* __restrict__ e) {
  const int lane = threadIdx.x & 63;
  const int wave = threadIdx.x >> 6;
  const int b    = blockIdx.x >> 5;
  const int r0   = (blockIdx.x & 31) * 32;  // row base within this b
  const float4* dec4 = (const float4*)(dec) + (size_t)b * 256;
  const float4* v4   = (const float4*)(v);
  float4 d[4], vv[4];
#pragma unroll
  for (int j = 0; j < 4; ++j) {
    d[j]  = dec4[lane + 64 * j];
    vv[j] = v4[lane + 64 * j];
  }
  const float4* efb = (const float4*)(ef) + ((size_t)b * LSRC + r0) * 256;
#pragma unroll
  for (int i = 0; i < 8; ++i) {
    int rl = wave + 4 * i;  // 4 waves read 4 consecutive rows per step
    const float4* row = efb + (size_t)rl * 256;
    float sum = 0.f;
#pragma unroll
    for (int j = 0; j < 4; ++j) {
      float4 x = row[lane + 64 * j];  // the only HBM stream: 4 loads/row/lane
      sum += fast_tanh(x.x + d[j].x) * vv[j].x;
      sum += fast_tanh(x.y + d[j].y) * vv[j].y;
      sum += fast_tanh(x.z + d[j].z) * vv[j].z;
      sum += fast_tanh(x.w + d[j].w) * vv[j].w;
    }
#pragma unroll
    for (int off = 32; off; off >>= 1) sum += __shfl_xor(sum, off);
    if (lane == 0) e[b * LSRC + r0 + rl] = sum;
  }
}

// attn[b][l] = exp(e-m)*mask / sum(exp(e-m)*mask)  (== softmax*mask renormalized)
__global__ __launch_bounds__(256) void softmax_kernel(
    const float* __restrict__ e, const float* __restrict__ mask,
    float* __restrict__ attn) {
  __shared__ float wmax[4], wsum[4];
  const int b = blockIdx.x, t = threadIdx.x;
  const int lane = t & 63, wave = t >> 6;
  float4 ev = ((const float4*)(e + b * LSRC))[t];
  float4 mk = ((const float4*)(mask + b * LSRC))[t];
  float m = fmaxf(fmaxf(ev.x, ev.y), fmaxf(ev.z, ev.w));
#pragma unroll
  for (int off = 32; off; off >>= 1) m = fmaxf(m, __shfl_xor(m, off));
  if (lane == 0) wmax[wave] = m;
  __syncthreads();
  m = fmaxf(fmaxf(wmax[0], wmax[1]), fmaxf(wmax[2], wmax[3]));
  float e0 = __expf(ev.x - m) * mk.x;
  float e1 = __expf(ev.y - m) * mk.y;
  float e2 = __expf(ev.z - m) * mk.z;
  float e3 = __expf(ev.w - m) * mk.w;
  float ssum = e0 + e1 + e2 + e3;
#pragma unroll
  for (int off = 32; off; off >>= 1) ssum += __shfl_xor(ssum, off);
  if (lane == 0) wsum[wave] = ssum;
  __syncthreads();
  float inv = 1.0f / (wsum[0] + wsum[1] + wsum[2] + wsum[3]);
  float4 o = {e0 * inv, e1 * inv, e2 * inv, e3 * inv};
  ((float4*)(attn + b * LSRC))[t] = o;
}

// part[lc][b][h] = sum_{l in chunk lc} attn[b][l] * eo[b][l][h]
// attn chunk staged in LDS (no scalar global loads in the stream loop).
__global__ __launch_bounds__(256) void ct_partial_kernel(
    const float* __restrict__ attn, const float* __restrict__ eo,
    float* __restrict__ part, int CH) {
  __shared__ float a_lds[128];
  const int lc = blockIdx.x;
  const int b  = blockIdx.y;
  const int t  = threadIdx.x;
  const int l0 = lc * CH;
  if (t < CH) a_lds[t] = attn[b * LSRC + l0 + t];
  __syncthreads();
  const float4* eob = (const float4*)(eo) + ((size_t)b * LSRC + l0) * 256;
  float4 acc = {0.f, 0.f, 0.f, 0.f};
#pragma unroll 8
  for (int l = 0; l < CH; ++l) {
    float  a = a_lds[l];                    // LDS broadcast, no vmcnt pressure
    float4 x = eob[(size_t)l * 256 + t];    // coalesced 1KB/wave HBM stream
    acc.x += a * x.x; acc.y += a * x.y; acc.z += a * x.z; acc.w += a * x.w;
  }
  ((float4*)(part) + (size_t)(lc * BATCH + b) * 256)[t] = acc;
}

// out[b][h] = sum_lc part[lc][b][h]
__global__ __launch_bounds__(256) void reduce_kernel(
    const float* __restrict__ part, float* __restrict__ out, int nch) {
  const int b = blockIdx.x, t = threadIdx.x;
  float4 s = {0.f, 0.f, 0.f, 0.f};
  for (int lc = 0; lc < nch; ++lc) {
    float4 x = ((const float4*)(part) + (size_t)(lc * BATCH + b) * 256)[t];
    s.x += x.x; s.y += x.y; s.z += x.z; s.w += x.w;
  }
  ((float4*)(out) + (size_t)b * 256)[t] = s;
}

extern "C" void kernel_launch(void* const* d_in, const int* in_sizes, int n_in,
                              void* d_out, int out_size, void* d_ws, size_t ws_size,
                              hipStream_t stream) {
  const float* s_t_hat  = (const float*)d_in[0];
  const float* enc_out  = (const float*)d_in[1];
  const float* enc_feat = (const float*)d_in[2];
  const float* mask     = (const float*)d_in[3];
  const float* W        = (const float*)d_in[4];
  const float* bias     = (const float*)d_in[5];
  const float* v        = (const float*)d_in[6];
  float* out = (float*)d_out;

  // ws layout (fp32): dec[64*1024] | e[64*1024] | attn[64*1024] | part[nch*64*1024]
  float* dec  = (float*)d_ws;
  float* e    = dec  + BATCH * H2;
  float* attn = e    + BATCH * LSRC;
  float* part = attn + BATCH * LSRC;

  // pick the most l-chunks the workspace can hold (deterministic: ws_size fixed)
  const size_t base  = (size_t)3 * BATCH * H2 * sizeof(float);
  const size_t chunk = (size_t)BATCH * H2 * sizeof(float);  // 256 KB per partial
  int nch = 8;
  if (ws_size >= base + 32 * chunk)      nch = 32;
  else if (ws_size >= base + 16 * chunk) nch = 16;
  const int CH = LSRC / nch;

  dec_kernel<<<H2 / 16, 256, 0, stream>>>(s_t_hat, W, bias, dec);
  e_kernel<<<BATCH * 32, 256, 0, stream>>>(enc_feat, dec, v, e);
  softmax_kernel<<<BATCH, 256, 0, stream>>>(e, mask, attn);
  ct_partial_kernel<<<dim3(nch, BATCH), 256, 0, stream>>>(attn, enc_out, part, CH);
  reduce_kernel<<<BATCH, 256, 0, stream>>>(part, out, nch);
}